// Round 1
// baseline (398.838 us; speedup 1.0000x reference)
//
#include <hip/hip_runtime.h>
#include <hip/hip_bf16.h>
#include <math.h>

#define T 4096
#define E 64
#define NH 8
#define BHN 16
#define NB 64   // buckets per sequence
#define BS 64   // bucket size

// ---------------------------------------------------------------------------
// K1: compute LSH buckets (argmax over [rot, -rot]) and per-row 1/||qk||.
// grid (T/64, BH, NH), block 64. One token per thread.
// ---------------------------------------------------------------------------
__global__ __launch_bounds__(64) void k_bucket(const float* __restrict__ qk,
                                               const float* __restrict__ rot,
                                               unsigned char* __restrict__ buckets,
                                               float* __restrict__ inv_norm) {
  __shared__ float sQ[64][65];
  const int tid = threadIdx.x;
  const int t0 = blockIdx.x * 64;
  const int bh = blockIdx.y;
  const int r  = blockIdx.z;
  const int b = bh >> 3, hh = bh & 7;
  const size_t gbase = (size_t)b * ((size_t)T * 8 * 64) + (size_t)hh * 64;

  for (int k = 0; k < 64; ++k)
    sQ[k][tid] = qk[gbase + (size_t)(t0 + k) * 512 + tid];
  __syncthreads();

  const int t = t0 + tid;
  if (r == 0) {
    float ss = 0.f;
    #pragma unroll
    for (int f = 0; f < 64; ++f) { float q = sQ[tid][f]; ss += q * q; }
    inv_norm[bh * T + t] = 1.0f / sqrtf(ss);
  }

  float acc[32];
  #pragma unroll
  for (int i = 0; i < 32; ++i) acc[i] = 0.f;
  for (int f = 0; f < 64; ++f) {
    float qv = sQ[tid][f];
    const float* rp = rot + (size_t)f * (NH * 32) + r * 32;
    #pragma unroll
    for (int i = 0; i < 32; ++i) acc[i] += qv * rp[i];
  }
  float maxv = -INFINITY, minv = INFINITY;
  int amax = 0, amin = 0;
  #pragma unroll
  for (int i = 0; i < 32; ++i) {
    if (acc[i] > maxv) { maxv = acc[i]; amax = i; }
    if (acc[i] < minv) { minv = acc[i]; amin = i; }
  }
  int bucket = (maxv >= -minv) ? amax : 32 + amin;  // first-occurrence tie: first half wins
  buckets[((size_t)r * BHN + bh) * T + t] = (unsigned char)bucket;
}

// ---------------------------------------------------------------------------
// K2: stable counting argsort of buckets per (hash, bh) segment.
// grid (NH*BH), block 1024 (16 waves). Deterministic, no atomics.
// ---------------------------------------------------------------------------
__global__ __launch_bounds__(1024) void k_sort(const unsigned char* __restrict__ buckets,
                                               int* __restrict__ perm,
                                               int* __restrict__ perm_inv) {
  __shared__ unsigned short bkt[T];
  __shared__ unsigned short rnk[T];
  __shared__ unsigned int cnt[64 * 64];   // [bucket][chunk]
  __shared__ unsigned int bbase[64];
  __shared__ unsigned int btot[64];

  const int tid = threadIdx.x;
  const int seg = blockIdx.x;
  const unsigned char* bin = buckets + (size_t)seg * T;

  for (int idx = tid; idx < T; idx += 1024) bkt[idx] = bin[idx];
  __syncthreads();

  const int wave = tid >> 6, lane = tid & 63;
  const unsigned long long lt = (1ull << lane) - 1ull;
  for (int cc = 0; cc < 4; ++cc) {
    int chunk = wave * 4 + cc;
    int e = bkt[chunk * 64 + lane];
    for (int bb = 0; bb < 64; ++bb) {
      unsigned long long m = __ballot(e == bb);
      if (lane == bb) cnt[bb * 64 + chunk] = (unsigned int)__popcll(m);
      if (e == bb) rnk[chunk * 64 + lane] = (unsigned short)__popcll(m & lt);
    }
  }
  __syncthreads();
  if (tid < 64) {
    unsigned int run = 0;
    for (int c = 0; c < 64; ++c) {
      unsigned int v = cnt[tid * 64 + c];
      cnt[tid * 64 + c] = run;
      run += v;
    }
    btot[tid] = run;
  }
  __syncthreads();
  if (tid == 0) {
    unsigned int run = 0;
    for (int bb = 0; bb < 64; ++bb) { bbase[bb] = run; run += btot[bb]; }
  }
  __syncthreads();
  for (int idx = tid; idx < T; idx += 1024) {
    int e = bkt[idx];
    int c = idx >> 6;
    int pos = (int)(bbase[e] + cnt[e * 64 + c] + rnk[idx]);
    perm[(size_t)seg * T + pos] = idx;
    perm_inv[(size_t)seg * T + idx] = pos;
  }
}

// ---------------------------------------------------------------------------
// K3: per-bucket attention. grid (NB, BH, NH), block 256.
// 64 queries x 128 keys (own bucket + previous bucket), self-masked,
// normalized keys, temp = 1/8 folded into q. fp32 throughout; p staged bf16.
// ---------------------------------------------------------------------------
__global__ __launch_bounds__(256) void k_attn(const float* __restrict__ qk,
                                              const float* __restrict__ vglob,
                                              const int* __restrict__ perm,
                                              const float* __restrict__ inv_norm,
                                              float* __restrict__ o_ws,
                                              float* __restrict__ lse_ws) {
  __shared__ __align__(16) float sQ[64 * 68];
  __shared__ __align__(16) float sKV[128 * 68];
  __shared__ int sIdx[128];
  __hip_bfloat16* sP = (__hip_bfloat16*)sQ;  // overlay: [64][132] bf16, used after scores

  const int tid = threadIdx.x;
  const int n  = blockIdx.x;
  const int bh = blockIdx.y;
  const int r  = blockIdx.z;
  const int b = bh >> 3, hh = bh & 7;
  const size_t gbase = (size_t)b * ((size_t)T * 8 * 64) + (size_t)hh * 64;
  const size_t ps = ((size_t)r * BHN + bh) * T;

  if (tid < 128) {
    int src = (tid < 64) ? (n * 64 + tid) : (((n + 63) & 63) * 64 + (tid - 64));
    sIdx[tid] = perm[ps + src];
  }
  __syncthreads();

  // stage q (x temp) and normalized k
  for (int idx = tid; idx < 64 * 64; idx += 256) {
    int i = idx >> 6, f = idx & 63;
    int t = sIdx[i];
    sQ[i * 68 + f] = qk[gbase + (size_t)t * 512 + f] * 0.125f;
  }
  for (int idx = tid; idx < 128 * 64; idx += 256) {
    int j = idx >> 6, f = idx & 63;
    int t = sIdx[j];
    sKV[j * 68 + f] = qk[gbase + (size_t)t * 512 + f] * inv_norm[bh * T + t];
  }
  __syncthreads();

  const int qg = tid >> 4;  // queries qg*4 + a
  const int kg = tid & 15;  // keys kg + 16*c

  float s[4][8];
  #pragma unroll
  for (int a = 0; a < 4; ++a)
    #pragma unroll
    for (int c = 0; c < 8; ++c) s[a][c] = 0.f;

  for (int f0 = 0; f0 < 64; f0 += 4) {
    float4 qreg[4], kreg[8];
    #pragma unroll
    for (int a = 0; a < 4; ++a) qreg[a] = *(const float4*)&sQ[(qg * 4 + a) * 68 + f0];
    #pragma unroll
    for (int c = 0; c < 8; ++c) kreg[c] = *(const float4*)&sKV[(kg + 16 * c) * 68 + f0];
    #pragma unroll
    for (int a = 0; a < 4; ++a)
      #pragma unroll
      for (int c = 0; c < 8; ++c)
        s[a][c] += qreg[a].x * kreg[c].x + qreg[a].y * kreg[c].y +
                   qreg[a].z * kreg[c].z + qreg[a].w * kreg[c].w;
  }

  // self-mask (exact token-id match; exactly one per query row)
  int qi[4];
  #pragma unroll
  for (int a = 0; a < 4; ++a) qi[a] = sIdx[qg * 4 + a];
  #pragma unroll
  for (int c = 0; c < 8; ++c) {
    int kj = sIdx[kg + 16 * c];
    #pragma unroll
    for (int a = 0; a < 4; ++a)
      if (kj == qi[a]) s[a][c] = -50000.0f;
  }

  // row softmax across 8 local + 16 lanes (same wave, xor 1/2/4/8)
  float m[4], l[4];
  #pragma unroll
  for (int a = 0; a < 4; ++a) {
    float mm = s[a][0];
    #pragma unroll
    for (int c = 1; c < 8; ++c) mm = fmaxf(mm, s[a][c]);
    mm = fmaxf(mm, __shfl_xor(mm, 1));
    mm = fmaxf(mm, __shfl_xor(mm, 2));
    mm = fmaxf(mm, __shfl_xor(mm, 4));
    mm = fmaxf(mm, __shfl_xor(mm, 8));
    m[a] = mm;
    float ll = 0.f;
    #pragma unroll
    for (int c = 0; c < 8; ++c) { s[a][c] = expf(s[a][c] - mm); ll += s[a][c]; }
    ll += __shfl_xor(ll, 1);
    ll += __shfl_xor(ll, 2);
    ll += __shfl_xor(ll, 4);
    ll += __shfl_xor(ll, 8);
    l[a] = ll;
  }
  __syncthreads();  // everyone done reading sQ/sKV

  // stage normalized probs (bf16) over sQ region; reload v over k region
  #pragma unroll
  for (int a = 0; a < 4; ++a) {
    float rcp = 1.0f / l[a];
    #pragma unroll
    for (int c = 0; c < 8; ++c)
      sP[(qg * 4 + a) * 132 + (kg + 16 * c)] = __float2bfloat16(s[a][c] * rcp);
    if (kg == 0)
      lse_ws[ps + qi[a]] = m[a] + logf(l[a]);
  }
  for (int idx = tid; idx < 128 * 64; idx += 256) {
    int j = idx >> 6, d = idx & 63;
    int t = sIdx[j];
    sKV[j * 68 + d] = vglob[gbase + (size_t)t * 512 + d];
  }
  __syncthreads();

  // PV: thread (qg, dg): 4 queries x 4 d over all 128 keys
  const int dg = kg;
  float acc[4][4];
  #pragma unroll
  for (int a = 0; a < 4; ++a)
    #pragma unroll
    for (int dd = 0; dd < 4; ++dd) acc[a][dd] = 0.f;

  for (int j0 = 0; j0 < 128; j0 += 4) {
    float pv[4][4];
    #pragma unroll
    for (int a = 0; a < 4; ++a) {
      const __hip_bfloat16* pp = &sP[(qg * 4 + a) * 132 + j0];
      #pragma unroll
      for (int jj = 0; jj < 4; ++jj) pv[a][jj] = __bfloat162float(pp[jj]);
    }
    #pragma unroll
    for (int jj = 0; jj < 4; ++jj) {
      float4 vv = *(const float4*)&sKV[(j0 + jj) * 68 + dg * 4];
      #pragma unroll
      for (int a = 0; a < 4; ++a) {
        acc[a][0] += pv[a][jj] * vv.x;
        acc[a][1] += pv[a][jj] * vv.y;
        acc[a][2] += pv[a][jj] * vv.z;
        acc[a][3] += pv[a][jj] * vv.w;
      }
    }
  }
  #pragma unroll
  for (int a = 0; a < 4; ++a) {
    float4 outv = make_float4(acc[a][0], acc[a][1], acc[a][2], acc[a][3]);
    size_t o = (ps + (size_t)qi[a]) * 64 + dg * 4;
    *(float4*)&o_ws[o] = outv;
  }
}

// ---------------------------------------------------------------------------
// K4: combine hashes: softmax over 8 lse per token, weighted sum of o rows.
// grid (BH*T*64/256), block 256.
// ---------------------------------------------------------------------------
__global__ __launch_bounds__(256) void k_combine(const float* __restrict__ o_ws,
                                                 const float* __restrict__ lse_ws,
                                                 float* __restrict__ out) {
  const int gid = blockIdx.x * 256 + threadIdx.x;
  const int d = gid & 63;
  const int row = gid >> 6;  // bh*T + t
  const int bh = row >> 12;
  const int t = row & (T - 1);

  float ls[8];
  float mm = -INFINITY;
  #pragma unroll
  for (int r = 0; r < 8; ++r) {
    ls[r] = lse_ws[((size_t)r * BHN + bh) * T + t];
    mm = fmaxf(mm, ls[r]);
  }
  float sum = 0.f;
  #pragma unroll
  for (int r = 0; r < 8; ++r) { ls[r] = expf(ls[r] - mm); sum += ls[r]; }
  float rcp = 1.0f / sum;

  float acc = 0.f;
  #pragma unroll
  for (int r = 0; r < 8; ++r)
    acc += ls[r] * o_ws[(((size_t)r * BHN + bh) * T + t) * 64 + d];
  acc *= rcp;

  const int b = bh >> 3, hh = bh & 7;
  out[(((size_t)b * T + t) * 8 + hh) * 64 + d] = acc;
}

// ---------------------------------------------------------------------------
extern "C" void kernel_launch(void* const* d_in, const int* in_sizes, int n_in,
                              void* d_out, int out_size, void* d_ws, size_t ws_size,
                              hipStream_t stream) {
  const float* qk  = (const float*)d_in[0];
  const float* v   = (const float*)d_in[1];
  const float* rot = (const float*)d_in[2];
  float* out = (float*)d_out;

  // workspace layout (bytes)
  char* ws = (char*)d_ws;
  float* o_ws          = (float*)(ws);                                   // 8*16*4096*64*4 = 134217728
  int* perm            = (int*)(ws + 134217728);                         // 8388608
  int* perm_inv        = (int*)(ws + 134217728 + 8388608);               // 8388608
  unsigned char* bkts  = (unsigned char*)(ws + 134217728 + 16777216);    // 524288
  float* lse_ws        = (float*)(ws + 134217728 + 16777216 + 524288);   // 2097152
  float* inv_norm      = (float*)(ws + 134217728 + 16777216 + 524288 + 2097152); // 262144
  // total = 153,878,528 bytes

  k_bucket<<<dim3(T / 64, BHN, NH), 64, 0, stream>>>(qk, rot, bkts, inv_norm);
  k_sort<<<dim3(NH * BHN), 1024, 0, stream>>>(bkts, perm, perm_inv);
  k_attn<<<dim3(NB, BHN, NH), 256, 0, stream>>>(qk, v, perm, inv_norm, o_ws, lse_ws);
  k_combine<<<dim3((BHN * T * 64) / 256), 256, 0, stream>>>(o_ws, lse_ws, out);
}

// Round 2
// 268.674 us; speedup vs baseline: 1.4845x; 1.4845x over previous
//
#include <hip/hip_runtime.h>
#include <hip/hip_bf16.h>
#include <math.h>

#define T 4096
#define E 64
#define NH 8
#define BHN 16
#define NB 64   // buckets per sequence
#define BS 64   // bucket size

using bf16x8 = __attribute__((ext_vector_type(8))) short;
using f32x4  = __attribute__((ext_vector_type(4))) float;

__device__ __forceinline__ f32x4 mfma16(bf16x8 a, bf16x8 b, f32x4 c) {
  return __builtin_amdgcn_mfma_f32_16x16x32_bf16(a, b, c, 0, 0, 0);
}

__device__ __forceinline__ unsigned short f2bf(float x) {
  unsigned u = __float_as_uint(x);
  unsigned r = u + 0x7fff + ((u >> 16) & 1);
  return (unsigned short)(r >> 16);
}
__device__ __forceinline__ float bf2f(unsigned short b) {
  return __uint_as_float(((unsigned)b) << 16);
}
__device__ __forceinline__ float f4get(const float4& v, int i) {
  return i == 0 ? v.x : i == 1 ? v.y : i == 2 ? v.z : v.w;
}

// byte-offset swizzles: rows of 128B / 256B, XOR row bits into 16B-slot bits
#define SWZ128(row, inb) ((((row)) << 7) + ((inb) ^ ((((row)) & 7) << 4)))
#define SWZ256(row, inb) ((((row)) << 8) + ((inb) ^ ((((row)) & 7) << 4)))

// ---------------------------------------------------------------------------
// K1: LSH buckets for all 8 hashes + per-row 1/||qk||. grid (T/64, BH), blk 64.
// ---------------------------------------------------------------------------
__global__ __launch_bounds__(64) void k_bucket(const float* __restrict__ qk,
                                               const float* __restrict__ rot,
                                               unsigned char* __restrict__ buckets,
                                               float* __restrict__ inv_norm) {
  __shared__ float sQ[64][65];
  const int tid = threadIdx.x;
  const int t0 = blockIdx.x * 64;
  const int bh = blockIdx.y;
  const int b = bh >> 3, hh = bh & 7;
  const size_t gbase = (size_t)b * ((size_t)T * 512) + (size_t)hh * 64;

  for (int k = 0; k < 64; ++k)
    sQ[k][tid] = qk[gbase + (size_t)(t0 + k) * 512 + tid];
  __syncthreads();

  const int t = t0 + tid;
  float ss = 0.f;
  #pragma unroll
  for (int f = 0; f < 64; ++f) { float q = sQ[tid][f]; ss += q * q; }
  inv_norm[bh * T + t] = 1.0f / sqrtf(ss);

  for (int r = 0; r < NH; ++r) {
    float acc[32];
    #pragma unroll
    for (int i = 0; i < 32; ++i) acc[i] = 0.f;
    for (int f = 0; f < 64; ++f) {
      float qv = sQ[tid][f];
      const float* rp = rot + (size_t)f * (NH * 32) + r * 32;
      #pragma unroll
      for (int i = 0; i < 32; ++i) acc[i] += qv * rp[i];
    }
    float maxv = -INFINITY, minv = INFINITY;
    int amax = 0, amin = 0;
    #pragma unroll
    for (int i = 0; i < 32; ++i) {
      if (acc[i] > maxv) { maxv = acc[i]; amax = i; }
      if (acc[i] < minv) { minv = acc[i]; amin = i; }
    }
    int bucket = (maxv >= -minv) ? amax : 32 + amin;
    buckets[((size_t)r * BHN + bh) * T + t] = (unsigned char)bucket;
  }
}

// ---------------------------------------------------------------------------
// K2: stable counting argsort per (hash, bh) segment. grid (NH*BH), block 1024.
// ---------------------------------------------------------------------------
__global__ __launch_bounds__(1024) void k_sort(const unsigned char* __restrict__ buckets,
                                               int* __restrict__ perm,
                                               int* __restrict__ perm_inv) {
  __shared__ unsigned short bkt[T];
  __shared__ unsigned short rnk[T];
  __shared__ unsigned int cnt[64 * 64];
  __shared__ unsigned int bbase[64];
  __shared__ unsigned int btot[64];

  const int tid = threadIdx.x;
  const int seg = blockIdx.x;
  const unsigned char* bin = buckets + (size_t)seg * T;

  for (int idx = tid; idx < T; idx += 1024) bkt[idx] = bin[idx];
  __syncthreads();

  const int wave = tid >> 6, lane = tid & 63;
  const unsigned long long lt = (1ull << lane) - 1ull;
  for (int cc = 0; cc < 4; ++cc) {
    int chunk = wave * 4 + cc;
    int e = bkt[chunk * 64 + lane];
    for (int bb = 0; bb < 64; ++bb) {
      unsigned long long m = __ballot(e == bb);
      if (lane == bb) cnt[bb * 64 + chunk] = (unsigned int)__popcll(m);
      if (e == bb) rnk[chunk * 64 + lane] = (unsigned short)__popcll(m & lt);
    }
  }
  __syncthreads();
  if (tid < 64) {
    unsigned int run = 0;
    for (int c = 0; c < 64; ++c) {
      unsigned int v = cnt[tid * 64 + c];
      cnt[tid * 64 + c] = run;
      run += v;
    }
    btot[tid] = run;
  }
  __syncthreads();
  if (tid == 0) {
    unsigned int run = 0;
    for (int bb = 0; bb < 64; ++bb) { bbase[bb] = run; run += btot[bb]; }
  }
  __syncthreads();
  for (int idx = tid; idx < T; idx += 1024) {
    int e = bkt[idx];
    int c = idx >> 6;
    int pos = (int)(bbase[e] + cnt[e * 64 + c] + rnk[idx]);
    perm[(size_t)seg * T + pos] = idx;
    perm_inv[(size_t)seg * T + idx] = pos;
  }
}

// ---------------------------------------------------------------------------
// K3: per-bucket attention via MFMA. grid (NB, BH, NH), block 256 (4 waves).
// 64 q x 128 k, E=D=64. Q 2-term bf16, K 1-term, P 1-term, V 2-term.
// ---------------------------------------------------------------------------
__global__ __launch_bounds__(256) void k_attn(const float* __restrict__ qk,
                                              const float* __restrict__ vglob,
                                              const int* __restrict__ perm,
                                              const float* __restrict__ inv_norm,
                                              float* __restrict__ o_ws,
                                              float* __restrict__ lse_ws) {
  __shared__ __align__(16) char smem[49664];
  constexpr int LQHI = 0;          // 64 rows x 128B  (bf16 [64][64])
  constexpr int LQLO = 8192;       // 64 rows x 128B
  constexpr int LKHI = 16384;      // 128 rows x 128B (bf16 [128][64])
  constexpr int LVTLO = 32768;     // 64 rows x 256B  (bf16 [64][128], V^T lo)
  constexpr int LIDX = 49152;      // 128 ints
  constexpr int LP   = 0;          // overlay: P bf16 [64][128] (64 x 256B)
  constexpr int LVTHI = 16384;     // overlay: V^T hi bf16 [64][128]
  constexpr int LO   = 0;          // overlay: O fp32 [64][64] (64 x 256B)
  int* sIdx = (int*)(smem + LIDX);

  const int tid = threadIdx.x;
  const int n = blockIdx.x, bh = blockIdx.y, r = blockIdx.z;
  const int b = bh >> 3, hh = bh & 7;
  const size_t gbase = (size_t)b * ((size_t)T * 512) + (size_t)hh * 64;
  const size_t ps = ((size_t)r * BHN + bh) * T;

  if (tid < 128) {
    int src = (tid < 64) ? (n * 64 + tid) : (((n + 63) & 63) * 64 + (tid - 64));
    sIdx[tid] = perm[ps + src];
  }
  __syncthreads();  // s1

  // ---- stage K (normalized, bf16 hi) and Q (x0.125, bf16 hi+lo) ----
  #pragma unroll
  for (int it = 0; it < 8; ++it) {
    int idx = it * 256 + tid;
    int tok = idx >> 4;
    int f0 = (idx & 15) * 4;
    int tt = sIdx[tok];
    float4 x = *(const float4*)&qk[gbase + (size_t)tt * 512 + f0];
    float inr = inv_norm[bh * T + tt];
    ushort4 kh;
    kh.x = f2bf(x.x * inr); kh.y = f2bf(x.y * inr);
    kh.z = f2bf(x.z * inr); kh.w = f2bf(x.w * inr);
    *(ushort4*)(smem + LKHI + SWZ128(tok, f0 * 2)) = kh;
    if (it < 4) {  // tok < 64: also a query row
      float q0 = x.x * 0.125f, q1 = x.y * 0.125f, q2 = x.z * 0.125f, q3 = x.w * 0.125f;
      ushort4 qh, ql;
      qh.x = f2bf(q0); ql.x = f2bf(q0 - bf2f(qh.x));
      qh.y = f2bf(q1); ql.y = f2bf(q1 - bf2f(qh.y));
      qh.z = f2bf(q2); ql.z = f2bf(q2 - bf2f(qh.z));
      qh.w = f2bf(q3); ql.w = f2bf(q3 - bf2f(qh.w));
      *(ushort4*)(smem + LQHI + SWZ128(tok, f0 * 2)) = qh;
      *(ushort4*)(smem + LQLO + SWZ128(tok, f0 * 2)) = ql;
    }
  }

  // ---- prefetch V into registers (in flight across the QK phase) ----
  float4 vreg[8];
  #pragma unroll
  for (int bb = 0; bb < 2; ++bb) {
    int blkid = bb * 256 + tid;
    int tok0 = (blkid & 31) * 4, d0 = (blkid >> 5) * 4;
    #pragma unroll
    for (int jj = 0; jj < 4; ++jj)
      vreg[bb * 4 + jj] = *(const float4*)&vglob[gbase + (size_t)sIdx[tok0 + jj] * 512 + d0];
  }
  __syncthreads();  // s2: Q/K staged

  const int wid = tid >> 6, lane = tid & 63;
  const int lr = lane & 15, lg = lane >> 4;

  // A fragments (Q rows 16w+lr, k = lg*8 + 32ks)
  bf16x8 a_hi[2], a_lo[2];
  #pragma unroll
  for (int ks = 0; ks < 2; ++ks) {
    a_hi[ks] = *(const bf16x8*)(smem + LQHI + SWZ128(16 * wid + lr, lg * 16 + ks * 64));
    a_lo[ks] = *(const bf16x8*)(smem + LQLO + SWZ128(16 * wid + lr, lg * 16 + ks * 64));
  }
  __syncthreads();  // s2.5: Q frags in regs everywhere (P will overwrite Q region)

  f32x4 c[8];
  #pragma unroll
  for (int t = 0; t < 8; ++t) c[t] = (f32x4){0.f, 0.f, 0.f, 0.f};
  #pragma unroll
  for (int t = 0; t < 8; ++t) {
    #pragma unroll
    for (int ks = 0; ks < 2; ++ks) {
      bf16x8 bk = *(const bf16x8*)(smem + LKHI + SWZ128(16 * t + lr, lg * 16 + ks * 64));
      c[t] = mfma16(a_hi[ks], bk, c[t]);
      c[t] = mfma16(a_lo[ks], bk, c[t]);
    }
  }

  // self-mask: C[row][col], row = 16w + 4lg + q, col = 16t + lr
  int qtok[4];
  #pragma unroll
  for (int q = 0; q < 4; ++q) qtok[q] = sIdx[16 * wid + 4 * lg + q];
  #pragma unroll
  for (int t = 0; t < 8; ++t) {
    int kt = sIdx[16 * t + lr];
    #pragma unroll
    for (int q = 0; q < 4; ++q)
      if (kt == qtok[q]) c[t][q] = -50000.0f;
  }

  // row softmax: in-lane over 8 tiles, cross-lane over low 4 lane bits
  float pm[4], pl[4];
  #pragma unroll
  for (int q = 0; q < 4; ++q) {
    float mm = c[0][q];
    #pragma unroll
    for (int t = 1; t < 8; ++t) mm = fmaxf(mm, c[t][q]);
    mm = fmaxf(mm, __shfl_xor(mm, 1));
    mm = fmaxf(mm, __shfl_xor(mm, 2));
    mm = fmaxf(mm, __shfl_xor(mm, 4));
    mm = fmaxf(mm, __shfl_xor(mm, 8));
    float ss = 0.f;
    #pragma unroll
    for (int t = 0; t < 8; ++t) { float e = __expf(c[t][q] - mm); c[t][q] = e; ss += e; }
    ss += __shfl_xor(ss, 1);
    ss += __shfl_xor(ss, 2);
    ss += __shfl_xor(ss, 4);
    ss += __shfl_xor(ss, 8);
    pm[q] = mm; pl[q] = ss;
  }

  // write normalized P (bf16) over the Q region; write lse
  #pragma unroll
  for (int q = 0; q < 4; ++q) {
    float rcp = 1.0f / pl[q];
    int row = 16 * wid + 4 * lg + q;
    #pragma unroll
    for (int t = 0; t < 8; ++t)
      *(unsigned short*)(smem + LP + SWZ256(row, (16 * t + lr) * 2)) =
          f2bf(c[t][q] * rcp);
    if (lr == 0)
      lse_ws[ps + qtok[q]] = pm[q] + __logf(pl[q]);
  }
  __syncthreads();  // s3: P written, all K reads done

  // ---- write V^T (hi/lo) from prefetched regs, over K region ----
  #pragma unroll
  for (int bb = 0; bb < 2; ++bb) {
    int blkid = bb * 256 + tid;
    int tok0 = (blkid & 31) * 4, d0 = (blkid >> 5) * 4;
    #pragma unroll
    for (int dd = 0; dd < 4; ++dd) {
      ushort4 hi, lo;
      float x0 = f4get(vreg[bb * 4 + 0], dd);
      float x1 = f4get(vreg[bb * 4 + 1], dd);
      float x2 = f4get(vreg[bb * 4 + 2], dd);
      float x3 = f4get(vreg[bb * 4 + 3], dd);
      hi.x = f2bf(x0); lo.x = f2bf(x0 - bf2f(hi.x));
      hi.y = f2bf(x1); lo.y = f2bf(x1 - bf2f(hi.y));
      hi.z = f2bf(x2); lo.z = f2bf(x2 - bf2f(hi.z));
      hi.w = f2bf(x3); lo.w = f2bf(x3 - bf2f(hi.w));
      *(ushort4*)(smem + LVTHI + SWZ256(d0 + dd, tok0 * 2)) = hi;
      *(ushort4*)(smem + LVTLO + SWZ256(d0 + dd, tok0 * 2)) = lo;
    }
  }
  __syncthreads();  // s4: V^T staged

  // ---- PV: A = P rows 16w+lr, B = V^T ----
  bf16x8 pa[4];
  #pragma unroll
  for (int ks = 0; ks < 4; ++ks)
    pa[ks] = *(const bf16x8*)(smem + LP + SWZ256(16 * wid + lr, lg * 16 + ks * 64));
  f32x4 o[4];
  #pragma unroll
  for (int t = 0; t < 4; ++t) o[t] = (f32x4){0.f, 0.f, 0.f, 0.f};
  #pragma unroll
  for (int t = 0; t < 4; ++t) {
    #pragma unroll
    for (int ks = 0; ks < 4; ++ks) {
      bf16x8 bhv = *(const bf16x8*)(smem + LVTHI + SWZ256(16 * t + lr, lg * 16 + ks * 64));
      o[t] = mfma16(pa[ks], bhv, o[t]);
      bf16x8 blv = *(const bf16x8*)(smem + LVTLO + SWZ256(16 * t + lr, lg * 16 + ks * 64));
      o[t] = mfma16(pa[ks], blv, o[t]);
    }
  }
  __syncthreads();  // s5: all P / V^T reads done

  // stage O (fp32) over P region for coalesced scatter
  #pragma unroll
  for (int t = 0; t < 4; ++t) {
    #pragma unroll
    for (int q = 0; q < 4; ++q)
      *(float*)(smem + LO + SWZ256(16 * wid + 4 * lg + q, (16 * t + lr) * 4)) = o[t][q];
  }
  __syncthreads();  // s6

  {
    int row = tid >> 2, cq = tid & 3;
    int tt = sIdx[row];
    size_t gb = (ps + (size_t)tt) * 64 + cq * 16;
    #pragma unroll
    for (int cc = 0; cc < 4; ++cc) {
      float4 val = *(const float4*)(smem + LO + SWZ256(row, cq * 64 + cc * 16));
      *(float4*)&o_ws[gb + cc * 4] = val;
    }
  }
}

// ---------------------------------------------------------------------------
// K4: combine hashes. grid (BH*T*64/256), block 256.
// ---------------------------------------------------------------------------
__global__ __launch_bounds__(256) void k_combine(const float* __restrict__ o_ws,
                                                 const float* __restrict__ lse_ws,
                                                 float* __restrict__ out) {
  const int gid = blockIdx.x * 256 + threadIdx.x;
  const int d = gid & 63;
  const int row = gid >> 6;
  const int bh = row >> 12;
  const int t = row & (T - 1);

  float ls[8];
  float mm = -INFINITY;
  #pragma unroll
  for (int r = 0; r < 8; ++r) {
    ls[r] = lse_ws[((size_t)r * BHN + bh) * T + t];
    mm = fmaxf(mm, ls[r]);
  }
  float sum = 0.f;
  #pragma unroll
  for (int r = 0; r < 8; ++r) { ls[r] = __expf(ls[r] - mm); sum += ls[r]; }
  float rcp = 1.0f / sum;

  float acc = 0.f;
  #pragma unroll
  for (int r = 0; r < 8; ++r)
    acc += ls[r] * o_ws[(((size_t)r * BHN + bh) * T + t) * 64 + d];
  acc *= rcp;

  const int b = bh >> 3, hh = bh & 7;
  out[(((size_t)b * T + t) * 8 + hh) * 64 + d] = acc;
}

// ---------------------------------------------------------------------------
extern "C" void kernel_launch(void* const* d_in, const int* in_sizes, int n_in,
                              void* d_out, int out_size, void* d_ws, size_t ws_size,
                              hipStream_t stream) {
  const float* qk  = (const float*)d_in[0];
  const float* v   = (const float*)d_in[1];
  const float* rot = (const float*)d_in[2];
  float* out = (float*)d_out;

  char* ws = (char*)d_ws;
  float* o_ws          = (float*)(ws);                                   // 134217728
  int* perm            = (int*)(ws + 134217728);                         // 8388608
  int* perm_inv        = (int*)(ws + 134217728 + 8388608);               // 8388608
  unsigned char* bkts  = (unsigned char*)(ws + 134217728 + 16777216);    // 524288
  float* lse_ws        = (float*)(ws + 134217728 + 16777216 + 524288);   // 2097152
  float* inv_norm      = (float*)(ws + 134217728 + 16777216 + 524288 + 2097152); // 262144

  k_bucket<<<dim3(T / 64, BHN), 64, 0, stream>>>(qk, rot, bkts, inv_norm);
  k_sort<<<dim3(NH * BHN), 1024, 0, stream>>>(bkts, perm, perm_inv);
  k_attn<<<dim3(NB, BHN, NH), 256, 0, stream>>>(qk, v, perm, inv_norm, o_ws, lse_ws);
  k_combine<<<dim3((BHN * T * 64) / 256), 256, 0, stream>>>(o_ws, lse_ws, out);
}